// Round 3
// baseline (264.293 us; speedup 1.0000x reference)
//
#include <hip/hip_runtime.h>
#include <hip/hip_bf16.h>
#include <math.h>

// SP_loss: s = X X^T / T (N=8192, D=256, T=0.04, groups of 4).
// loss = mean_g softplus((neg[g] - margin[g]) / T)
//   neg[g]    = T * log sum_{i in g, j not in g} exp(s[i,j])
//               -> symmetric bf16 MFMA GEMM over upper-tri 128x128 tiles,
//                  double-buffered BK=32, fused exp + row/col-sum,
//                  last-block finalization (device-scope counter).
//   margin[g] = exact fp32 4x4 group Gram block (hard_pos / least_pos / alpha)

#define NROWS 8192
#define DDIM  256
#define NGRP  2048
#define NTB   64          // 8192 / 128 tile-blocks per dim
#define NTILES (NTB * (NTB + 1) / 2)
#define T_CONST 0.04f
#define INV_T   25.0f
#define EXP2_SCALE 36.06737602222409f   // 25 * log2(e)

typedef __attribute__((ext_vector_type(8))) short bf16x8_t;
typedef __attribute__((ext_vector_type(4))) float f32x4_t;

typedef const __attribute__((address_space(1))) void gv_t;
typedef __attribute__((address_space(3))) void lv_t;

__device__ __forceinline__ unsigned short f2bf_rne(float f) {
    unsigned int u = __float_as_uint(f);
    unsigned int r = 0x7fffu + ((u >> 16) & 1u);
    return (unsigned short)((u + r) >> 16);
}

__device__ __forceinline__ void gll16(const unsigned short* g, unsigned short* l) {
    __builtin_amdgcn_global_load_lds((gv_t*)g, (lv_t*)l, 16, 0, 0);
}

// Kernel A (fused prep): blocks 0..2047 convert fp32->bf16 (RNE) + zero rowsum
// and the completion counter; blocks 2048..2559 compute margin[g] (4 groups/block).
__global__ __launch_bounds__(256) void prep_kernel(const float* __restrict__ x,
                                                   unsigned short* __restrict__ xb,
                                                   float* __restrict__ rowsum,
                                                   float* __restrict__ margin,
                                                   unsigned int* __restrict__ counter) {
    const int b = blockIdx.x;
    if (b < 2048) {
        int gid = b * 256 + threadIdx.x;
        int i = gid * 4;
        float4 v = *(const float4*)(x + i);
        ushort4 o;
        o.x = f2bf_rne(v.x); o.y = f2bf_rne(v.y); o.z = f2bf_rne(v.z); o.w = f2bf_rne(v.w);
        *(ushort4*)(xb + i) = o;
        if (gid < NROWS) rowsum[gid] = 0.f;
        if (gid == 0) *counter = 0u;
        return;
    }
    const int g = (b - 2048) * 4 + (threadIdx.x >> 6);
    const int lane = threadIdx.x & 63;
    const float* xr = x + (size_t)g * 4 * DDIM;
    float a[16];
#pragma unroll
    for (int k = 0; k < 16; ++k) a[k] = 0.f;
    for (int e = lane; e < DDIM; e += 64) {
        float vv[4];
        vv[0] = xr[e];
        vv[1] = xr[DDIM + e];
        vv[2] = xr[2 * DDIM + e];
        vv[3] = xr[3 * DDIM + e];
#pragma unroll
        for (int i = 0; i < 4; ++i)
#pragma unroll
            for (int j = 0; j < 4; ++j)
                a[i * 4 + j] = fmaf(vv[i], vv[j], a[i * 4 + j]);
    }
#pragma unroll
    for (int k = 0; k < 16; ++k) {
        float t = a[k];
        t += __shfl_xor(t, 32, 64);
        t += __shfl_xor(t, 16, 64);
        t += __shfl_xor(t, 8, 64);
        t += __shfl_xor(t, 4, 64);
        t += __shfl_xor(t, 2, 64);
        t += __shfl_xor(t, 1, 64);
        a[k] = t;
    }
    if (lane == 0) {
        float pos[16];
#pragma unroll
        for (int k = 0; k < 16; ++k) pos[k] = a[k] * INV_T;

        float mx = -pos[0];
#pragma unroll
        for (int k = 1; k < 16; ++k) mx = fmaxf(mx, -pos[k]);
        float se = 0.f;
#pragma unroll
        for (int k = 0; k < 16; ++k) se += __expf(-pos[k] - mx);
        float hard_pos = -T_CONST * (mx + __logf(se));

        float lse_row[4];
#pragma unroll
        for (int i = 0; i < 4; ++i) {
            float m2 = -pos[i * 4];
#pragma unroll
            for (int j = 1; j < 4; ++j) m2 = fmaxf(m2, -pos[i * 4 + j]);
            float s2 = 0.f;
#pragma unroll
            for (int j = 0; j < 4; ++j) s2 += __expf(-pos[i * 4 + j] - m2);
            lse_row[i] = m2 + __logf(s2);
        }
        float m3 = -lse_row[0];
#pragma unroll
        for (int i = 1; i < 4; ++i) m3 = fmaxf(m3, -lse_row[i]);
        float s3 = 0.f;
#pragma unroll
        for (int i = 0; i < 4; ++i) s3 += __expf(-lse_row[i] - m3);
        float least_pos = T_CONST * (m3 + __logf(s3));

        float alpha = (hard_pos >= 0.f)
                          ? (2.f * least_pos * hard_pos) / (hard_pos + least_pos)
                          : 0.f;
        margin[g] = alpha * hard_pos + (1.f - alpha) * least_pos;
    }
}

// Kernel B: symmetric fused bf16 GEMM over upper-tri 128x128 tiles (2080 blocks).
// Double-buffered BK=32; prefetch issued right after the barrier so the next
// barrier's implicit vmcnt(0) waits on loads that are a full MFMA-iteration old.
// XOR-swizzled LDS (bank-conflict-free ds_read_b128, verified R2: conflicts=0).
// Off-diag: no mask, exp feeds rowsum[row] and rowsum[col]. Diag: group mask.
// Last block to finish computes the loss (device-scope counter + atomic loads).
__global__ __launch_bounds__(256) void gemm_exp_rowsum(const unsigned short* __restrict__ xb,
                                                       float* __restrict__ rowsum,
                                                       const float* __restrict__ margin,
                                                       unsigned int* __restrict__ counter,
                                                       float* __restrict__ out) {
    __shared__ unsigned short Als[2][128 * 32];
    __shared__ unsigned short Bls[2][128 * 32];
    __shared__ float rowacc[128];
    __shared__ float colacc[128];
    __shared__ unsigned int lastFlag;

    // decode upper-triangular (bi, bj), bi <= bj: offset(bi) = bi*(129-bi)/2
    const int idx = blockIdx.x;
    int bi = (int)((129.0f - sqrtf(16641.0f - 8.0f * (float)idx)) * 0.5f);
    while (bi * (129 - bi) / 2 > idx) --bi;
    while ((bi + 1) * (128 - bi) / 2 <= idx) ++bi;
    const int bj = bi + (idx - bi * (129 - bi) / 2);
    const int row0 = bi * 128;
    const int col0 = bj * 128;
    const bool diag = (bi == bj);

    const int tid = threadIdx.x;
    const int lane = tid & 63;
    const int w = tid >> 6;
    const int wrow = (w >> 1) * 64;
    const int wcol = (w & 1) * 64;
    const int quad = lane >> 4;
    const int l16 = lane & 15;
    const int swz = (l16 >> 1) & 3;
    const int srow = tid >> 2;                       // staging row 0..63
    const int kc = (tid & 3) ^ ((tid >> 3) & 3);     // swizzled k-chunk

    if (tid < 128) { rowacc[tid] = 0.f; colacc[tid] = 0.f; }

    f32x4_t acc[4][4];
#pragma unroll
    for (int i = 0; i < 4; ++i)
#pragma unroll
        for (int j = 0; j < 4; ++j)
            acc[i][j] = (f32x4_t){0.f, 0.f, 0.f, 0.f};

    const unsigned short* ga = xb + (size_t)(row0 + srow) * DDIM + kc * 8;
    const unsigned short* gb = xb + (size_t)(col0 + srow) * DDIM + kc * 8;

    // prologue: fill buffer 0
    gll16(ga,             &Als[0][tid * 8]);
    gll16(ga + 64 * DDIM, &Als[0][2048 + tid * 8]);
    gll16(gb,             &Bls[0][tid * 8]);
    gll16(gb + 64 * DDIM, &Bls[0][2048 + tid * 8]);

    for (int kb = 0; kb < 8; ++kb) {
        const int cur = kb & 1;
        __syncthreads();   // implicit vmcnt(0): exactly the loads filling buf[cur]
        if (kb < 7) {      // prefetch next BK into the other buffer (readers done)
            const int ko = (kb + 1) * 32;
            gll16(ga + ko,             &Als[cur ^ 1][tid * 8]);
            gll16(ga + ko + 64 * DDIM, &Als[cur ^ 1][2048 + tid * 8]);
            gll16(gb + ko,             &Bls[cur ^ 1][tid * 8]);
            gll16(gb + ko + 64 * DDIM, &Bls[cur ^ 1][2048 + tid * 8]);
        }
        bf16x8_t aF[4], bF[4];
#pragma unroll
        for (int mi = 0; mi < 4; ++mi)
            aF[mi] = *(const bf16x8_t*)&Als[cur][(wrow + mi * 16 + l16) * 32 + (quad ^ swz) * 8];
#pragma unroll
        for (int ni = 0; ni < 4; ++ni)
            bF[ni] = *(const bf16x8_t*)&Bls[cur][(wcol + ni * 16 + l16) * 32 + (quad ^ swz) * 8];
#pragma unroll
        for (int mi = 0; mi < 4; ++mi)
#pragma unroll
            for (int ni = 0; ni < 4; ++ni)
                acc[mi][ni] = __builtin_amdgcn_mfma_f32_16x16x32_bf16(aF[mi], bF[ni],
                                                                      acc[mi][ni], 0, 0, 0);
    }

    // Epilogue. C/D layout: col = wcol + ni*16 + l16, row = wrow + mi*16 + quad*4 + reg.
    if (!diag) {
        float colv[4] = {0.f, 0.f, 0.f, 0.f};
#pragma unroll
        for (int mi = 0; mi < 4; ++mi) {
#pragma unroll
            for (int reg = 0; reg < 4; ++reg) {
                const int lrow = wrow + mi * 16 + quad * 4 + reg;
                float rv = 0.f;
#pragma unroll
                for (int ni = 0; ni < 4; ++ni) {
                    float e = exp2f(acc[mi][ni][reg] * EXP2_SCALE);
                    rv += e;
                    colv[ni] += e;
                }
                rv += __shfl_xor(rv, 1, 64);
                rv += __shfl_xor(rv, 2, 64);
                rv += __shfl_xor(rv, 4, 64);
                rv += __shfl_xor(rv, 8, 64);
                if (l16 == 0) atomicAdd(&rowacc[lrow], rv);
            }
        }
#pragma unroll
        for (int ni = 0; ni < 4; ++ni) {
            float cv = colv[ni];
            cv += __shfl_xor(cv, 16, 64);
            cv += __shfl_xor(cv, 32, 64);
            if (quad == 0) atomicAdd(&colacc[wcol + ni * 16 + l16], cv);
        }
    } else {
#pragma unroll
        for (int mi = 0; mi < 4; ++mi) {
#pragma unroll
            for (int reg = 0; reg < 4; ++reg) {
                const int lrow = wrow + mi * 16 + quad * 4 + reg;
                const int grp = (row0 + lrow) >> 2;
                float rv = 0.f;
#pragma unroll
                for (int ni = 0; ni < 4; ++ni) {
                    const int gcol = col0 + wcol + ni * 16 + l16;
                    rv += ((gcol >> 2) == grp) ? 0.f : exp2f(acc[mi][ni][reg] * EXP2_SCALE);
                }
                rv += __shfl_xor(rv, 1, 64);
                rv += __shfl_xor(rv, 2, 64);
                rv += __shfl_xor(rv, 4, 64);
                rv += __shfl_xor(rv, 8, 64);
                if (l16 == 0) atomicAdd(&rowacc[lrow], rv);
            }
        }
    }
    __syncthreads();
    if (tid < 128) {
        atomicAdd(&rowsum[row0 + tid], rowacc[tid]);
        if (!diag) atomicAdd(&rowsum[col0 + tid], colacc[tid]);
    }

    // ---- last-block finalization ----
    __threadfence();           // order this block's rowsum atomics before counter bump
    __syncthreads();
    if (tid == 0) {
        unsigned int prev = __hip_atomic_fetch_add(counter, 1u, __ATOMIC_ACQ_REL,
                                                   __HIP_MEMORY_SCOPE_AGENT);
        lastFlag = (prev == (unsigned int)(NTILES - 1)) ? 1u : 0u;
    }
    __syncthreads();
    if (lastFlag) {
        float local = 0.f;
        for (int g = tid; g < NGRP; g += 256) {
            float s = 0.f;
#pragma unroll
            for (int r = 0; r < 4; ++r)
                s += __hip_atomic_load(&rowsum[4 * g + r], __ATOMIC_RELAXED,
                                       __HIP_MEMORY_SCOPE_AGENT);
            float z = __logf(s) - margin[g] * INV_T;   // (neg - margin)/T
            float sp = (z > 30.f) ? z : log1pf(__expf(z));
            local += sp;
        }
        local += __shfl_xor(local, 1, 64);
        local += __shfl_xor(local, 2, 64);
        local += __shfl_xor(local, 4, 64);
        local += __shfl_xor(local, 8, 64);
        local += __shfl_xor(local, 16, 64);
        local += __shfl_xor(local, 32, 64);
        __shared__ float wsum[4];
        if ((tid & 63) == 0) wsum[tid >> 6] = local;
        __syncthreads();
        if (tid == 0) out[0] = (wsum[0] + wsum[1] + wsum[2] + wsum[3]) * (1.f / (float)NGRP);
    }
}

extern "C" void kernel_launch(void* const* d_in, const int* in_sizes, int n_in,
                              void* d_out, int out_size, void* d_ws, size_t ws_size,
                              hipStream_t stream) {
    const float* x = (const float*)d_in[0];
    float* out = (float*)d_out;

    unsigned short* xb = (unsigned short*)d_ws;                              // 4 MiB bf16 X
    float* rowsum = (float*)((char*)d_ws + (size_t)NROWS * DDIM * 2);        // 32 KiB
    float* margin = rowsum + NROWS;                                          // 8 KiB
    unsigned int* counter = (unsigned int*)(margin + NGRP);                  // 4 B

    prep_kernel<<<2048 + 512, 256, 0, stream>>>(x, xb, rowsum, margin, counter);
    gemm_exp_rowsum<<<NTILES, 256, 0, stream>>>(xb, rowsum, margin, counter, out);
}

// Round 4
// 250.164 us; speedup vs baseline: 1.0565x; 1.0565x over previous
//
#include <hip/hip_runtime.h>
#include <math.h>

// SP_loss: s = X X^T / T (N=8192, D=256, T=0.04, groups of 4).
// loss = mean_g softplus((neg[g] - margin[g]) / T)
//   neg[g]    = T * log sum_{i in g, j not in g} exp(s[i,j])
//               -> MX-fp8 (e4m3, K=128 scaled MFMA) symmetric GEMM over
//                  upper-tri 128x128 tiles, whole-K LDS (single barrier),
//                  fused exp + row/col-sum, last-block finalization.
//   margin[g] = exact fp32 4x4 group Gram block (hard_pos / least_pos / alpha)
//
// X is pre-scaled by 16 into fp8 (elements ~N(0,1) -> all normals, rel err <= 2^-4);
// MFMA E8M0 scales of 2^-4 per operand undo the 16*16=256 factor exactly in HW.

#define NROWS 8192
#define DDIM  256
#define NGRP  2048
#define NTB   64
#define NTILES (NTB * (NTB + 1) / 2)   // 2080
#define T_CONST 0.04f
#define INV_T   25.0f
#define EXP2_SCALE 36.06737602222409f  // 25 * log2(e)
#define SCALE_QTR 0x7B7B7B7Bu          // E8M0 123 = 2^-4 in every byte (opsel-proof)

typedef __attribute__((ext_vector_type(8))) int   i32x8_t;
typedef __attribute__((ext_vector_type(4))) int   i32x4_t;
typedef __attribute__((ext_vector_type(4))) float f32x4_t;

typedef const __attribute__((address_space(1))) void gv_t;
typedef __attribute__((address_space(3))) void lv_t;

__device__ __forceinline__ void gll16(const void* g, void* l) {
    __builtin_amdgcn_global_load_lds((gv_t*)g, (lv_t*)l, 16, 0, 0);
}

// Kernel A (fused prep): blocks 0..2047 convert fp32 -> fp8 e4m3 (x*16, RNE) +
// zero rowsum + counter; blocks 2048..2559 compute margin[g] (4 groups/block).
__global__ __launch_bounds__(256) void prep_kernel(const float* __restrict__ x,
                                                   unsigned int* __restrict__ xq,
                                                   float* __restrict__ rowsum,
                                                   float* __restrict__ margin,
                                                   unsigned int* __restrict__ counter) {
    const int b = blockIdx.x;
    if (b < 2048) {
        int gid = b * 256 + threadIdx.x;
        float4 v = *(const float4*)(x + gid * 4);
        int pk = __builtin_amdgcn_cvt_pk_fp8_f32(v.x * 16.f, v.y * 16.f, 0, false);
        pk = __builtin_amdgcn_cvt_pk_fp8_f32(v.z * 16.f, v.w * 16.f, pk, true);
        xq[gid] = (unsigned int)pk;
        if (gid < NROWS) rowsum[gid] = 0.f;
        if (gid == 0) *counter = 0u;
        return;
    }
    const int g = (b - 2048) * 4 + (threadIdx.x >> 6);
    const int lane = threadIdx.x & 63;
    const float* xr = x + (size_t)g * 4 * DDIM;
    float a[16];
#pragma unroll
    for (int k = 0; k < 16; ++k) a[k] = 0.f;
    for (int e = lane; e < DDIM; e += 64) {
        float vv[4];
        vv[0] = xr[e];
        vv[1] = xr[DDIM + e];
        vv[2] = xr[2 * DDIM + e];
        vv[3] = xr[3 * DDIM + e];
#pragma unroll
        for (int i = 0; i < 4; ++i)
#pragma unroll
            for (int j = 0; j < 4; ++j)
                a[i * 4 + j] = fmaf(vv[i], vv[j], a[i * 4 + j]);
    }
#pragma unroll
    for (int k = 0; k < 16; ++k) {
        float t = a[k];
        t += __shfl_xor(t, 32, 64);
        t += __shfl_xor(t, 16, 64);
        t += __shfl_xor(t, 8, 64);
        t += __shfl_xor(t, 4, 64);
        t += __shfl_xor(t, 2, 64);
        t += __shfl_xor(t, 1, 64);
        a[k] = t;
    }
    if (lane == 0) {
        float pos[16];
#pragma unroll
        for (int k = 0; k < 16; ++k) pos[k] = a[k] * INV_T;

        float mx = -pos[0];
#pragma unroll
        for (int k = 1; k < 16; ++k) mx = fmaxf(mx, -pos[k]);
        float se = 0.f;
#pragma unroll
        for (int k = 0; k < 16; ++k) se += __expf(-pos[k] - mx);
        float hard_pos = -T_CONST * (mx + __logf(se));

        float lse_row[4];
#pragma unroll
        for (int i = 0; i < 4; ++i) {
            float m2 = -pos[i * 4];
#pragma unroll
            for (int j = 1; j < 4; ++j) m2 = fmaxf(m2, -pos[i * 4 + j]);
            float s2 = 0.f;
#pragma unroll
            for (int j = 0; j < 4; ++j) s2 += __expf(-pos[i * 4 + j] - m2);
            lse_row[i] = m2 + __logf(s2);
        }
        float m3 = -lse_row[0];
#pragma unroll
        for (int i = 1; i < 4; ++i) m3 = fmaxf(m3, -lse_row[i]);
        float s3 = 0.f;
#pragma unroll
        for (int i = 0; i < 4; ++i) s3 += __expf(-lse_row[i] - m3);
        float least_pos = T_CONST * (m3 + __logf(s3));

        float alpha = (hard_pos >= 0.f)
                          ? (2.f * least_pos * hard_pos) / (hard_pos + least_pos)
                          : 0.f;
        margin[g] = alpha * hard_pos + (1.f - alpha) * least_pos;
    }
}

// Kernel B: symmetric MX-fp8 GEMM over upper-tri 128x128 tiles (2080 blocks).
// Whole K=256 for both tiles staged in 64 KB LDS via 16 global_load_lds ->
// a SINGLE vmcnt-draining barrier per block (no gll-after-barrier: R3's
// compiler-vmcnt trap avoided). 2 k-steps of 16x16x128 scaled MFMA.
// Source-side granule swizzle (g3 ^ row&7) -> fragment ds_read_b128 2-way (free).
// rowacc/colacc/wsum alias onto Als (dead after MFMA) -> static LDS = 64 KB exact.
__global__ __launch_bounds__(256, 2) void gemm_exp_rowsum(const unsigned char* __restrict__ xq,
                                                          float* __restrict__ rowsum,
                                                          const float* __restrict__ margin,
                                                          unsigned int* __restrict__ counter,
                                                          float* __restrict__ out) {
    __shared__ unsigned char Als[128 * 256];   // 32 KB: A tile, full K
    __shared__ unsigned char Bls[128 * 256];   // 32 KB: B tile, full K

    // decode upper-triangular (bi, bj), bi <= bj: offset(bi) = bi*(129-bi)/2
    const int idx = blockIdx.x;
    int bi = (int)((129.0f - sqrtf(16641.0f - 8.0f * (float)idx)) * 0.5f);
    while (bi * (129 - bi) / 2 > idx) --bi;
    while ((bi + 1) * (128 - bi) / 2 <= idx) ++bi;
    const int bj = bi + (idx - bi * (129 - bi) / 2);
    const int row0 = bi * 128;
    const int col0 = bj * 128;
    const bool diag = (bi == bj);

    const int tid = threadIdx.x;
    const int lane = tid & 63;
    const int w = tid >> 6;
    const int wrow = (w >> 1) * 64;
    const int wcol = (w & 1) * 64;
    const int quad = lane >> 4;
    const int l16 = lane & 15;

    // ---- stage both tiles, full K, swizzled at the source ----
    const int p = tid & 15;     // LDS granule slot within row
    const int rr = tid >> 4;    // row within 16-row chunk
#pragma unroll
    for (int c = 0; c < 8; ++c) {
        const int srow = c * 16 + rr;
        const int g = (p & 8) | ((p & 7) ^ (srow & 7));   // source granule for slot p
        const size_t goff = (size_t)g * 16;
        gll16(xq + ((size_t)(row0 + srow) << 8) + goff, &Als[c * 4096 + tid * 16]);
        gll16(xq + ((size_t)(col0 + srow) << 8) + goff, &Bls[c * 4096 + tid * 16]);
    }

    f32x4_t acc[4][4];
#pragma unroll
    for (int i = 0; i < 4; ++i)
#pragma unroll
        for (int j = 0; j < 4; ++j)
            acc[i][j] = (f32x4_t){0.f, 0.f, 0.f, 0.f};

    __syncthreads();   // the one vmcnt(0) drain: all 64 KB staged

#pragma unroll
    for (int ks = 0; ks < 2; ++ks) {
        i32x8_t aF[4], bF[4];
#pragma unroll
        for (int mi = 0; mi < 4; ++mi) {
            const int m = wrow + mi * 16 + l16;
            const int base = m * 256 + ks * 128;
            i32x4_t lo = *(const i32x4_t*)&Als[base + (((2 * quad) ^ (m & 7)) << 4)];
            i32x4_t hi = *(const i32x4_t*)&Als[base + (((2 * quad + 1) ^ (m & 7)) << 4)];
            aF[mi] = __builtin_shufflevector(lo, hi, 0, 1, 2, 3, 4, 5, 6, 7);
        }
#pragma unroll
        for (int ni = 0; ni < 4; ++ni) {
            const int n = wcol + ni * 16 + l16;
            const int base = n * 256 + ks * 128;
            i32x4_t lo = *(const i32x4_t*)&Bls[base + (((2 * quad) ^ (n & 7)) << 4)];
            i32x4_t hi = *(const i32x4_t*)&Bls[base + (((2 * quad + 1) ^ (n & 7)) << 4)];
            bF[ni] = __builtin_shufflevector(lo, hi, 0, 1, 2, 3, 4, 5, 6, 7);
        }
#pragma unroll
        for (int mi = 0; mi < 4; ++mi)
#pragma unroll
            for (int ni = 0; ni < 4; ++ni)
                acc[mi][ni] = __builtin_amdgcn_mfma_scale_f32_16x16x128_f8f6f4(
                    aF[mi], bF[ni], acc[mi][ni],
                    0, 0,                       // cbsz/blgp: fp8 e4m3 A and B
                    0, (int)SCALE_QTR,          // scale A = 2^-4
                    0, (int)SCALE_QTR);         // scale B = 2^-4
    }

    // ---- LDS tiles dead; alias accumulators onto Als ----
    __syncthreads();
    float* rowacc = (float*)&Als[0];                       // 512 B
    float* colacc = (float*)&Als[512];                     // 512 B
    float* wsumS = (float*)&Als[1024];                     // 16 B
    unsigned int* lastFlag = (unsigned int*)&Als[1040];
    if (tid < 128) { rowacc[tid] = 0.f; colacc[tid] = 0.f; }
    __syncthreads();

    // Epilogue. C/D layout: col = wcol + ni*16 + l16, row = wrow + mi*16 + quad*4 + reg.
    if (!diag) {
        float colv[4] = {0.f, 0.f, 0.f, 0.f};
#pragma unroll
        for (int mi = 0; mi < 4; ++mi) {
#pragma unroll
            for (int reg = 0; reg < 4; ++reg) {
                const int lrow = wrow + mi * 16 + quad * 4 + reg;
                float rv = 0.f;
#pragma unroll
                for (int ni = 0; ni < 4; ++ni) {
                    float e = exp2f(acc[mi][ni][reg] * EXP2_SCALE);
                    rv += e;
                    colv[ni] += e;
                }
                rv += __shfl_xor(rv, 1, 64);
                rv += __shfl_xor(rv, 2, 64);
                rv += __shfl_xor(rv, 4, 64);
                rv += __shfl_xor(rv, 8, 64);
                if (l16 == 0) atomicAdd(&rowacc[lrow], rv);
            }
        }
#pragma unroll
        for (int ni = 0; ni < 4; ++ni) {
            float cv = colv[ni];
            cv += __shfl_xor(cv, 16, 64);
            cv += __shfl_xor(cv, 32, 64);
            if (quad == 0) atomicAdd(&colacc[wcol + ni * 16 + l16], cv);
        }
    } else {
#pragma unroll
        for (int mi = 0; mi < 4; ++mi) {
#pragma unroll
            for (int reg = 0; reg < 4; ++reg) {
                const int lrow = wrow + mi * 16 + quad * 4 + reg;
                const int grp = (row0 + lrow) >> 2;
                float rv = 0.f;
#pragma unroll
                for (int ni = 0; ni < 4; ++ni) {
                    const int gcol = col0 + wcol + ni * 16 + l16;
                    rv += ((gcol >> 2) == grp) ? 0.f : exp2f(acc[mi][ni][reg] * EXP2_SCALE);
                }
                rv += __shfl_xor(rv, 1, 64);
                rv += __shfl_xor(rv, 2, 64);
                rv += __shfl_xor(rv, 4, 64);
                rv += __shfl_xor(rv, 8, 64);
                if (l16 == 0) atomicAdd(&rowacc[lrow], rv);
            }
        }
    }
    __syncthreads();
    if (tid < 128) {
        atomicAdd(&rowsum[row0 + tid], rowacc[tid]);
        if (!diag) atomicAdd(&rowsum[col0 + tid], colacc[tid]);
    }

    // ---- last-block finalization ----
    __threadfence();           // order rowsum atomics before counter bump
    __syncthreads();
    if (tid == 0) {
        unsigned int prev = __hip_atomic_fetch_add(counter, 1u, __ATOMIC_ACQ_REL,
                                                   __HIP_MEMORY_SCOPE_AGENT);
        *lastFlag = (prev == (unsigned int)(NTILES - 1)) ? 1u : 0u;
    }
    __syncthreads();
    if (*lastFlag) {
        float local = 0.f;
        for (int g = tid; g < NGRP; g += 256) {
            float s = 0.f;
#pragma unroll
            for (int r = 0; r < 4; ++r)
                s += __hip_atomic_load(&rowsum[4 * g + r], __ATOMIC_RELAXED,
                                       __HIP_MEMORY_SCOPE_AGENT);
            float z = __logf(s) - margin[g] * INV_T;   // (neg - margin)/T
            float sp = (z > 30.f) ? z : log1pf(__expf(z));
            local += sp;
        }
        local += __shfl_xor(local, 1, 64);
        local += __shfl_xor(local, 2, 64);
        local += __shfl_xor(local, 4, 64);
        local += __shfl_xor(local, 8, 64);
        local += __shfl_xor(local, 16, 64);
        local += __shfl_xor(local, 32, 64);
        if ((tid & 63) == 0) wsumS[tid >> 6] = local;
        __syncthreads();
        if (tid == 0) out[0] = (wsumS[0] + wsumS[1] + wsumS[2] + wsumS[3]) * (1.f / (float)NGRP);
    }
}

extern "C" void kernel_launch(void* const* d_in, const int* in_sizes, int n_in,
                              void* d_out, int out_size, void* d_ws, size_t ws_size,
                              hipStream_t stream) {
    const float* x = (const float*)d_in[0];
    float* out = (float*)d_out;

    unsigned int* xq = (unsigned int*)d_ws;                                  // 2 MiB fp8 X*16
    float* rowsum = (float*)((char*)d_ws + (size_t)NROWS * DDIM);            // 32 KiB
    float* margin = rowsum + NROWS;                                          // 8 KiB
    unsigned int* counter = (unsigned int*)(margin + NGRP);                  // 4 B

    prep_kernel<<<2048 + 512, 256, 0, stream>>>(x, xq, rowsum, margin, counter);
    gemm_exp_rowsum<<<NTILES, 256, 0, stream>>>((const unsigned char*)xq, rowsum,
                                                margin, counter, out);
}

// Round 5
// 110.120 us; speedup vs baseline: 2.4000x; 2.2717x over previous
//
#include <hip/hip_runtime.h>
#include <math.h>

// SP_loss: s = X X^T / T (N=8192, D=256, T=0.04, groups of 4).
// loss = mean_g softplus((neg[g] - margin[g]) / T)
//   neg[g]    = T * log sum_{i in g, j not in g} exp(s[i,j])
//               -> MX-fp8 (e4m3, K=128 scaled MFMA) symmetric GEMM over
//                  upper-tri 128x128 tiles, BK=128 x 2 iters (32 KB LDS),
//                  fused exp + row/col-sum into global atomics.
//   margin[g] = exact fp32 4x4 group Gram block (hard_pos / least_pos / alpha)
//
// NO device-scope fences anywhere: R3/R4 showed per-block agent-scope
// release (threadfence / ACQ_REL atomic) emits buffer_wbl2 (L2 writeback,
// required by non-coherent per-XCD L2s) -> ~180 us regression. Finalize is
// a separate tiny kernel; kernel boundaries provide the ordering.
//
// X is pre-scaled by 16 into fp8 (elements ~N(0,1) -> all normals); MFMA E8M0
// scales of 2^-4 per operand undo the 16*16=256 factor exactly in HW
// (verified R4: absmax 0.0).

#define NROWS 8192
#define DDIM  256
#define NGRP  2048
#define NTB   64
#define NTILES (NTB * (NTB + 1) / 2)   // 2080
#define T_CONST 0.04f
#define INV_T   25.0f
#define EXP2_SCALE 36.06737602222409f  // 25 * log2(e)
#define SCALE_QTR 0x7B7B7B7Bu          // E8M0 123 = 2^-4 in every byte

typedef __attribute__((ext_vector_type(8))) int   i32x8_t;
typedef __attribute__((ext_vector_type(4))) int   i32x4_t;
typedef __attribute__((ext_vector_type(4))) float f32x4_t;

typedef const __attribute__((address_space(1))) void gv_t;
typedef __attribute__((address_space(3))) void lv_t;

__device__ __forceinline__ void gll16(const void* g, void* l) {
    __builtin_amdgcn_global_load_lds((gv_t*)g, (lv_t*)l, 16, 0, 0);
}

// Kernel A (fused prep): blocks 0..2047 convert fp32 -> fp8 e4m3 (x*16, RNE) +
// zero rowsum; blocks 2048..2559 compute margin[g] (4 groups/block, 1 wave each).
__global__ __launch_bounds__(256) void prep_kernel(const float* __restrict__ x,
                                                   unsigned int* __restrict__ xq,
                                                   float* __restrict__ rowsum,
                                                   float* __restrict__ margin) {
    const int b = blockIdx.x;
    if (b < 2048) {
        int gid = b * 256 + threadIdx.x;
        float4 v = *(const float4*)(x + gid * 4);
        int pk = __builtin_amdgcn_cvt_pk_fp8_f32(v.x * 16.f, v.y * 16.f, 0, false);
        pk = __builtin_amdgcn_cvt_pk_fp8_f32(v.z * 16.f, v.w * 16.f, pk, true);
        xq[gid] = (unsigned int)pk;
        if (gid < NROWS) rowsum[gid] = 0.f;
        return;
    }
    const int g = (b - 2048) * 4 + (threadIdx.x >> 6);
    const int lane = threadIdx.x & 63;
    const float* xr = x + (size_t)g * 4 * DDIM;
    float a[16];
#pragma unroll
    for (int k = 0; k < 16; ++k) a[k] = 0.f;
    for (int e = lane; e < DDIM; e += 64) {
        float vv[4];
        vv[0] = xr[e];
        vv[1] = xr[DDIM + e];
        vv[2] = xr[2 * DDIM + e];
        vv[3] = xr[3 * DDIM + e];
#pragma unroll
        for (int i = 0; i < 4; ++i)
#pragma unroll
            for (int j = 0; j < 4; ++j)
                a[i * 4 + j] = fmaf(vv[i], vv[j], a[i * 4 + j]);
    }
#pragma unroll
    for (int k = 0; k < 16; ++k) {
        float t = a[k];
        t += __shfl_xor(t, 32, 64);
        t += __shfl_xor(t, 16, 64);
        t += __shfl_xor(t, 8, 64);
        t += __shfl_xor(t, 4, 64);
        t += __shfl_xor(t, 2, 64);
        t += __shfl_xor(t, 1, 64);
        a[k] = t;
    }
    if (lane == 0) {
        float pos[16];
#pragma unroll
        for (int k = 0; k < 16; ++k) pos[k] = a[k] * INV_T;

        float mx = -pos[0];
#pragma unroll
        for (int k = 1; k < 16; ++k) mx = fmaxf(mx, -pos[k]);
        float se = 0.f;
#pragma unroll
        for (int k = 0; k < 16; ++k) se += __expf(-pos[k] - mx);
        float hard_pos = -T_CONST * (mx + __logf(se));

        float lse_row[4];
#pragma unroll
        for (int i = 0; i < 4; ++i) {
            float m2 = -pos[i * 4];
#pragma unroll
            for (int j = 1; j < 4; ++j) m2 = fmaxf(m2, -pos[i * 4 + j]);
            float s2 = 0.f;
#pragma unroll
            for (int j = 0; j < 4; ++j) s2 += __expf(-pos[i * 4 + j] - m2);
            lse_row[i] = m2 + __logf(s2);
        }
        float m3 = -lse_row[0];
#pragma unroll
        for (int i = 1; i < 4; ++i) m3 = fmaxf(m3, -lse_row[i]);
        float s3 = 0.f;
#pragma unroll
        for (int i = 0; i < 4; ++i) s3 += __expf(-lse_row[i] - m3);
        float least_pos = T_CONST * (m3 + __logf(s3));

        float alpha = (hard_pos >= 0.f)
                          ? (2.f * least_pos * hard_pos) / (hard_pos + least_pos)
                          : 0.f;
        margin[g] = alpha * hard_pos + (1.f - alpha) * least_pos;
    }
}

// Kernel B: symmetric MX-fp8 GEMM over upper-tri 128x128 tiles (2080 blocks).
// BK=128, 2 k-iterations, 32 KB LDS (A+B tiles) -> ~4 blocks/CU. R2-verified
// loop ordering: gll -> barrier -> ds_read (no gll between barrier and reads,
// so the compiler's vmcnt(0) lands only on the intended drain).
// Source-side granule swizzle (g = p ^ (srow&7)) -> fragment ds_read_b128
// nearly conflict-free (R4: 4 cyc/instr residual, negligible).
// Off-diag: no mask, exp feeds rowsum[row] and rowsum[col]. Diag: group mask.
__global__ __launch_bounds__(256) void gemm_exp_rowsum(const unsigned char* __restrict__ xq,
                                                       float* __restrict__ rowsum) {
    __shared__ unsigned char Als[128 * 128];   // 16 KB: A tile, one BK
    __shared__ unsigned char Bls[128 * 128];   // 16 KB: B tile, one BK
    __shared__ float rowacc[128];
    __shared__ float colacc[128];

    // decode upper-triangular (bi, bj), bi <= bj: offset(bi) = bi*(129-bi)/2
    const int idx = blockIdx.x;
    int bi = (int)((129.0f - sqrtf(16641.0f - 8.0f * (float)idx)) * 0.5f);
    while (bi * (129 - bi) / 2 > idx) --bi;
    while ((bi + 1) * (128 - bi) / 2 <= idx) ++bi;
    const int bj = bi + (idx - bi * (129 - bi) / 2);
    const int row0 = bi * 128;
    const int col0 = bj * 128;
    const bool diag = (bi == bj);

    const int tid = threadIdx.x;
    const int lane = tid & 63;
    const int w = tid >> 6;
    const int wrow = (w >> 1) * 64;
    const int wcol = (w & 1) * 64;
    const int quad = lane >> 4;
    const int l16 = lane & 15;
    const int p = tid & 7;               // staging granule slot within 128-B row

    if (tid < 128) { rowacc[tid] = 0.f; colacc[tid] = 0.f; }

    f32x4_t acc[4][4];
#pragma unroll
    for (int i = 0; i < 4; ++i)
#pragma unroll
        for (int j = 0; j < 4; ++j)
            acc[i][j] = (f32x4_t){0.f, 0.f, 0.f, 0.f};

#pragma unroll
    for (int ks = 0; ks < 2; ++ks) {
        if (ks) __syncthreads();         // prev iteration's fragment reads done
#pragma unroll
        for (int i = 0; i < 4; ++i) {    // stage A: 1024 granules, 4/thread
            const int gi = i * 256 + tid;
            const int srow = gi >> 3;
            const int g = p ^ (srow & 7);
            gll16(xq + ((size_t)(row0 + srow) << 8) + ks * 128 + g * 16, &Als[gi * 16]);
        }
#pragma unroll
        for (int i = 0; i < 4; ++i) {    // stage B
            const int gi = i * 256 + tid;
            const int srow = gi >> 3;
            const int g = p ^ (srow & 7);
            gll16(xq + ((size_t)(col0 + srow) << 8) + ks * 128 + g * 16, &Bls[gi * 16]);
        }
        __syncthreads();                 // the vmcnt(0) drain: tiles staged

        i32x8_t aF[4], bF[4];
#pragma unroll
        for (int mi = 0; mi < 4; ++mi) {
            const int m = wrow + mi * 16 + l16;
            const int base = m * 128;
            i32x4_t lo = *(const i32x4_t*)&Als[base + (((2 * quad) ^ (m & 7)) << 4)];
            i32x4_t hi = *(const i32x4_t*)&Als[base + (((2 * quad + 1) ^ (m & 7)) << 4)];
            aF[mi] = __builtin_shufflevector(lo, hi, 0, 1, 2, 3, 4, 5, 6, 7);
        }
#pragma unroll
        for (int ni = 0; ni < 4; ++ni) {
            const int n = wcol + ni * 16 + l16;
            const int base = n * 128;
            i32x4_t lo = *(const i32x4_t*)&Bls[base + (((2 * quad) ^ (n & 7)) << 4)];
            i32x4_t hi = *(const i32x4_t*)&Bls[base + (((2 * quad + 1) ^ (n & 7)) << 4)];
            bF[ni] = __builtin_shufflevector(lo, hi, 0, 1, 2, 3, 4, 5, 6, 7);
        }
#pragma unroll
        for (int mi = 0; mi < 4; ++mi)
#pragma unroll
            for (int ni = 0; ni < 4; ++ni)
                acc[mi][ni] = __builtin_amdgcn_mfma_scale_f32_16x16x128_f8f6f4(
                    aF[mi], bF[ni], acc[mi][ni],
                    0, 0,                       // cbsz/blgp: fp8 e4m3 A and B
                    0, (int)SCALE_QTR,          // scale A = 2^-4
                    0, (int)SCALE_QTR);         // scale B = 2^-4
    }

    // Epilogue. C/D layout: col = wcol + ni*16 + l16, row = wrow + mi*16 + quad*4 + reg.
    if (!diag) {
        float colv[4] = {0.f, 0.f, 0.f, 0.f};
#pragma unroll
        for (int mi = 0; mi < 4; ++mi) {
#pragma unroll
            for (int reg = 0; reg < 4; ++reg) {
                const int lrow = wrow + mi * 16 + quad * 4 + reg;
                float rv = 0.f;
#pragma unroll
                for (int ni = 0; ni < 4; ++ni) {
                    float e = exp2f(acc[mi][ni][reg] * EXP2_SCALE);
                    rv += e;
                    colv[ni] += e;
                }
                rv += __shfl_xor(rv, 1, 64);
                rv += __shfl_xor(rv, 2, 64);
                rv += __shfl_xor(rv, 4, 64);
                rv += __shfl_xor(rv, 8, 64);
                if (l16 == 0) atomicAdd(&rowacc[lrow], rv);
            }
        }
#pragma unroll
        for (int ni = 0; ni < 4; ++ni) {
            float cv = colv[ni];
            cv += __shfl_xor(cv, 16, 64);
            cv += __shfl_xor(cv, 32, 64);
            if (quad == 0) atomicAdd(&colacc[wcol + ni * 16 + l16], cv);
        }
    } else {
#pragma unroll
        for (int mi = 0; mi < 4; ++mi) {
#pragma unroll
            for (int reg = 0; reg < 4; ++reg) {
                const int lrow = wrow + mi * 16 + quad * 4 + reg;
                const int grp = (row0 + lrow) >> 2;
                float rv = 0.f;
#pragma unroll
                for (int ni = 0; ni < 4; ++ni) {
                    const int gcol = col0 + wcol + ni * 16 + l16;
                    rv += ((gcol >> 2) == grp) ? 0.f : exp2f(acc[mi][ni][reg] * EXP2_SCALE);
                }
                rv += __shfl_xor(rv, 1, 64);
                rv += __shfl_xor(rv, 2, 64);
                rv += __shfl_xor(rv, 4, 64);
                rv += __shfl_xor(rv, 8, 64);
                if (l16 == 0) atomicAdd(&rowacc[lrow], rv);
            }
        }
    }
    __syncthreads();
    if (tid < 128) {
        atomicAdd(&rowsum[row0 + tid], rowacc[tid]);     // device-scope, no fence
        if (!diag) atomicAdd(&rowsum[col0 + tid], colacc[tid]);
    }
}

// Kernel C: neg[g] = T*log(sum of 4 row sums); loss = mean softplus((neg-margin)/T).
__global__ __launch_bounds__(256) void finalize_kernel(const float* __restrict__ rowsum,
                                                       const float* __restrict__ margin,
                                                       float* __restrict__ out) {
    const int tid = threadIdx.x;
    float local = 0.f;
    for (int g = tid; g < NGRP; g += 256) {
        float s = rowsum[4 * g] + rowsum[4 * g + 1] + rowsum[4 * g + 2] + rowsum[4 * g + 3];
        float z = __logf(s) - margin[g] * INV_T;   // (neg - margin)/T
        float sp = (z > 30.f) ? z : log1pf(__expf(z));
        local += sp;
    }
    local += __shfl_xor(local, 1, 64);
    local += __shfl_xor(local, 2, 64);
    local += __shfl_xor(local, 4, 64);
    local += __shfl_xor(local, 8, 64);
    local += __shfl_xor(local, 16, 64);
    local += __shfl_xor(local, 32, 64);
    __shared__ float wsum[4];
    if ((tid & 63) == 0) wsum[tid >> 6] = local;
    __syncthreads();
    if (tid == 0) out[0] = (wsum[0] + wsum[1] + wsum[2] + wsum[3]) * (1.f / (float)NGRP);
}

extern "C" void kernel_launch(void* const* d_in, const int* in_sizes, int n_in,
                              void* d_out, int out_size, void* d_ws, size_t ws_size,
                              hipStream_t stream) {
    const float* x = (const float*)d_in[0];
    float* out = (float*)d_out;

    unsigned int* xq = (unsigned int*)d_ws;                                  // 2 MiB fp8 X*16
    float* rowsum = (float*)((char*)d_ws + (size_t)NROWS * DDIM);            // 32 KiB
    float* margin = rowsum + NROWS;                                          // 8 KiB

    prep_kernel<<<2048 + 512, 256, 0, stream>>>(x, xq, rowsum, margin);
    gemm_exp_rowsum<<<NTILES, 256, 0, stream>>>((const unsigned char*)xq, rowsum);
    finalize_kernel<<<1, 256, 0, stream>>>(rowsum, margin, out);
}